// Round 4
// baseline (270.564 us; speedup 1.0000x reference)
//
#include <hip/hip_runtime.h>
#include <math.h>

// STFT: inputs [64, 262144] f32, frame_length=8, frame_step=4, periodic Hann.
// num_frames = (262144-8)/4 + 1 = 65535, bins = 5.
// out = concat(magnitude[64,5,65535], phase[64,5,65535]) flat f32.
//
// R3 (resubmit after infra timeout): round-2 restructure (4 frames/thread,
// float4 loads, v_sqrt mags) + round-1 phase path (libm atan2f — proven
// correct on this input in round 1).

#define B 64
#define T 262144
#define NUM_FRAMES 65535
#define BINS 5
#define FPT 4               // frames per thread
#define NT 16384            // thread groups per row: 65536/4 (last group has 3 valid frames)

__global__ __launch_bounds__(256) void stft_kernel(const float* __restrict__ in,
                                                   float* __restrict__ out) {
    const int t = blockIdx.x * 256 + threadIdx.x;   // thread group index, 0..NT-1
    const int b = blockIdx.y;
    const int f0 = t * FPT;                         // first frame handled

    // Samples needed: [4*f0, 4*f0 + 20) = 5 aligned float4 (base = 64*t bytes).
    const float4* p = (const float4*)(in + (size_t)b * T + (size_t)f0 * 4);
    float x[20];
    float4 v;
    v = p[0]; x[0]=v.x; x[1]=v.y; x[2]=v.z; x[3]=v.w;
    v = p[1]; x[4]=v.x; x[5]=v.y; x[6]=v.z; x[7]=v.w;
    v = p[2]; x[8]=v.x; x[9]=v.y; x[10]=v.z; x[11]=v.w;
    v = p[3]; x[12]=v.x; x[13]=v.y; x[14]=v.z; x[15]=v.w;
    if (t < NT - 1) {                                // 5th vector would run past row end
        v = p[4]; x[16]=v.x; x[17]=v.y; x[18]=v.z; x[19]=v.w;
    } else {
        x[16]=0.f; x[17]=0.f; x[18]=0.f; x[19]=0.f;
    }

    const size_t plane = (size_t)NUM_FRAMES;
    float* magb = out + (size_t)b * BINS * plane;
    float* phb  = magb + (size_t)B * BINS * plane;

    const float w1 = 0.14644660940672624f;  // 0.5 - 0.5*cos(pi/4)
    const float w3 = 0.85355339059327376f;  // 0.5 - 0.5*cos(3pi/4)
    const float c  = 0.70710678118654752f;  // sqrt(2)/2

#pragma unroll
    for (int g = 0; g < FPT; ++g) {
        const int f = f0 + g;
        if (f >= NUM_FRAMES) continue;      // only group t=NT-1, g=3

        const float x1 = x[4*g + 1] * w1;
        const float x2 = x[4*g + 2] * 0.5f;
        const float x3 = x[4*g + 3] * w3;
        const float x4 = x[4*g + 4];        // w=1; x[4*g+0] has w=0
        const float x5 = x[4*g + 5] * w3;
        const float x6 = x[4*g + 6] * 0.5f;
        const float x7 = x[4*g + 7] * w1;

        const float s1  = x1 - x3 - x5 + x7;
        const float s2  = x1 + x3 - x5 - x7;
        const float d26 = x2 - x6;

        const float re0 = x1 + x2 + x3 + x4 + x5 + x6 + x7;
        const float re1 = -x4 + c * s1;
        const float im1 = -c * s2 - d26;
        const float re2 = -x2 + x4 - x6;
        const float im2 = -(x1 - x3 + x5 - x7);
        const float re3 = -x4 - c * s1;
        const float im3 = -c * s2 + d26;
        const float re4 = -x1 + x2 - x3 + x4 - x5 + x6 - x7;

        magb[0 * plane + f] = __builtin_fabsf(re0);
        magb[1 * plane + f] = __builtin_amdgcn_sqrtf(fmaf(re1, re1, im1 * im1));
        magb[2 * plane + f] = __builtin_amdgcn_sqrtf(fmaf(re2, re2, im2 * im2));
        magb[3 * plane + f] = __builtin_amdgcn_sqrtf(fmaf(re3, re3, im3 * im3));
        magb[4 * plane + f] = __builtin_fabsf(re4);

        // Round-1-proven phase path: libm atan2f on identical re/im bits.
        phb[0 * plane + f] = atan2f(0.0f, re0);
        phb[1 * plane + f] = atan2f(im1, re1);
        phb[2 * plane + f] = atan2f(im2, re2);
        phb[3 * plane + f] = atan2f(im3, re3);
        phb[4 * plane + f] = atan2f(0.0f, re4);
    }
}

extern "C" void kernel_launch(void* const* d_in, const int* in_sizes, int n_in,
                              void* d_out, int out_size, void* d_ws, size_t ws_size,
                              hipStream_t stream) {
    (void)in_sizes; (void)n_in; (void)d_ws; (void)ws_size; (void)out_size;
    const float* in = (const float*)d_in[0];
    float* out = (float*)d_out;

    dim3 block(256);
    dim3 grid(NT / 256, B);   // 64 x 64 = 4096 blocks
    stft_kernel<<<grid, block, 0, stream>>>(in, out);
}

// Round 5
// 250.667 us; speedup vs baseline: 1.0794x; 1.0794x over previous
//
#include <hip/hip_runtime.h>
#include <math.h>

// STFT: inputs [64, 262144] f32, frame_length=8, frame_step=4, periodic Hann.
// num_frames = (262144-8)/4 + 1 = 65535, bins = 5.
// out = concat(magnitude[64,5,65535], phase[64,5,65535]) flat f32.
//
// R5: dense-store mapping. Each wave owns 256 consecutive frames; thread's
// 4 frames are interleaved (f = wave*256 + g*64 + lane) so every global
// store instruction is lane-stride-1 (256 B contiguous per wave) — fixes
// R4's 2.33x WRITE_SIZE amplification from 4B-every-16B partial-sector
// stores. Compute path bit-identical to R4 (passed, absmax 0.0156).

#define B 64
#define T 262144
#define NUM_FRAMES 65535
#define BINS 5

__global__ __launch_bounds__(256) void stft_kernel(const float* __restrict__ in,
                                                   float* __restrict__ out) {
    const int lane = threadIdx.x & 63;
    const int wave = (blockIdx.x * 256 + threadIdx.x) >> 6;  // 0..255 per row
    const int b = blockIdx.y;

    const float* __restrict__ row = in + (size_t)b * T;
    const size_t plane = (size_t)NUM_FRAMES;
    float* __restrict__ magb = out + (size_t)b * BINS * plane;
    float* __restrict__ phb  = magb + (size_t)B * BINS * plane;

    const float w1 = 0.14644660940672624f;  // 0.5 - 0.5*cos(pi/4)
    const float w3 = 0.85355339059327376f;  // 0.5 - 0.5*cos(3pi/4)
    const float c  = 0.70710678118654752f;  // sqrt(2)/2

#pragma unroll
    for (int g = 0; g < 4; ++g) {
        const int f = wave * 256 + g * 64 + lane;          // frame index
        const int fl = (f < NUM_FRAMES) ? f : (NUM_FRAMES - 1);  // clamp load only

        // Frame fl starts at sample 4*fl (16 B aligned): two aligned float4.
        const float4 lo = *(const float4*)(row + 4 * fl);
        const float4 hi = *(const float4*)(row + 4 * fl + 4);

        const float x1 = lo.y * w1;
        const float x2 = lo.z * 0.5f;
        const float x3 = lo.w * w3;
        const float x4 = hi.x;          // w=1; lo.x has w=0
        const float x5 = hi.y * w3;
        const float x6 = hi.z * 0.5f;
        const float x7 = hi.w * w1;

        const float s1  = x1 - x3 - x5 + x7;
        const float s2  = x1 + x3 - x5 - x7;
        const float d26 = x2 - x6;

        const float re0 = x1 + x2 + x3 + x4 + x5 + x6 + x7;
        const float re1 = -x4 + c * s1;
        const float im1 = -c * s2 - d26;
        const float re2 = -x2 + x4 - x6;
        const float im2 = -(x1 - x3 + x5 - x7);
        const float re3 = -x4 - c * s1;
        const float im3 = -c * s2 + d26;
        const float re4 = -x1 + x2 - x3 + x4 - x5 + x6 - x7;

        if (f < NUM_FRAMES) {   // only global frame 65535 is invalid
            magb[0 * plane + f] = __builtin_fabsf(re0);
            magb[1 * plane + f] = __builtin_amdgcn_sqrtf(fmaf(re1, re1, im1 * im1));
            magb[2 * plane + f] = __builtin_amdgcn_sqrtf(fmaf(re2, re2, im2 * im2));
            magb[3 * plane + f] = __builtin_amdgcn_sqrtf(fmaf(re3, re3, im3 * im3));
            magb[4 * plane + f] = __builtin_fabsf(re4);

            phb[0 * plane + f] = atan2f(0.0f, re0);
            phb[1 * plane + f] = atan2f(im1, re1);
            phb[2 * plane + f] = atan2f(im2, re2);
            phb[3 * plane + f] = atan2f(im3, re3);
            phb[4 * plane + f] = atan2f(0.0f, re4);
        }
    }
}

extern "C" void kernel_launch(void* const* d_in, const int* in_sizes, int n_in,
                              void* d_out, int out_size, void* d_ws, size_t ws_size,
                              hipStream_t stream) {
    (void)in_sizes; (void)n_in; (void)d_ws; (void)ws_size; (void)out_size;
    const float* in = (const float*)d_in[0];
    float* out = (float*)d_out;

    dim3 block(256);
    dim3 grid(64, B);   // 64 blocks/row x 64 rows; 256 waves/row x 256 frames/wave
    stft_kernel<<<grid, block, 0, stream>>>(in, out);
}